// Round 2
// baseline (532.976 us; speedup 1.0000x reference)
//
#include <hip/hip_runtime.h>

#define B_   8
#define C_   256
#define H_   96
#define W_   128
#define HW_  (H_ * W_)          // 12288
#define PATCH_ 21
#define MAXD_  20
#define P2_  (W_ + 2 * MAXD_)   // 168 staged positions per row
#define KC_  8                  // channels staged per step
#define NDY_ 11                 // ceil(21/2) dy-pairs per (b,h)

typedef __fp16 half2_t __attribute__((ext_vector_type(2)));
typedef __fp16 h8_t    __attribute__((ext_vector_type(8)));

__device__ __forceinline__ float fdot2f(half2_t a, half2_t b, float c) {
#if __has_builtin(__builtin_amdgcn_fdot2)
  return __builtin_amdgcn_fdot2(a, b, c, false);
#else
  return c + (float)a.x * (float)b.x + (float)a.y * (float)b.y;
#endif
}

__global__ __launch_bounds__(64) void corr_kernel(
    const float* __restrict__ in1,
    const float* __restrict__ in2,
    float* __restrict__ out) {
  __shared__ h8_t lds[2][P2_];   // [half-wave's dy][position]: 8 halves = KC_ channels

  const int lane = threadIdx.x;      // 0..63
  const int hf   = lane >> 5;        // which dy of the pair
  const int wl   = lane & 31;

  const int bid = blockIdx.x;
  const int dyb = bid % NDY_;
  const int h   = (bid / NDY_) % H_;
  const int b   = bid / (NDY_ * H_);

  const int dyi = dyb * 2 + hf;            // 0..21 (21 is padding, masked at store)
  const int h2  = h + 2 * dyi - MAXD_;     // in2 source row
  const bool rowok = ((unsigned)h2 < (unsigned)H_);

  float acc[4][PATCH_];
#pragma unroll
  for (int t = 0; t < 4; ++t)
#pragma unroll
    for (int d = 0; d < PATCH_; ++d) acc[t][d] = 0.f;

  const size_t in1_row = ((size_t)b * C_ * H_ + (size_t)h) * W_;
  const size_t in2_row = rowok ? (((size_t)b * C_ * H_ + (size_t)h2) * W_) : 0;

  for (int c0 = 0; c0 < C_; c0 += KC_) {
    __syncthreads();
    // ---- stage this half-wave's in2 row chunk (KC_ channels, f32 -> packed f16) ----
    for (int p = wl; p < P2_; p += 32) {
      const int w2 = p - MAXD_;
      const bool v = rowok && ((unsigned)w2 < (unsigned)W_);
      const size_t base = v ? (in2_row + (size_t)c0 * HW_ + (size_t)w2) : 0;
      float f[KC_];
#pragma unroll
      for (int j = 0; j < KC_; ++j) {
        float x = in2[base + (size_t)j * HW_];
        f[j] = v ? x : 0.f;
      }
      h8_t pk;
#pragma unroll
      for (int jj = 0; jj < 4; ++jj) {
        half2_t q = __builtin_amdgcn_cvt_pkrtz(f[2 * jj], f[2 * jj + 1]);
        pk[2 * jj]     = q.x;
        pk[2 * jj + 1] = q.y;
      }
      lds[hf][p] = pk;
    }
    __syncthreads();

    // ---- A fragments: this thread's 4 w positions (w = wl + 32t), 8 channels ----
    float fA[KC_][4];
#pragma unroll
    for (int j = 0; j < KC_; ++j) {
      const float* ap = in1 + in1_row + (size_t)(c0 + j) * HW_;
#pragma unroll
      for (int t = 0; t < 4; ++t) fA[j][t] = ap[wl + 32 * t];
    }
    half2_t a2[4][4];
#pragma unroll
    for (int t = 0; t < 4; ++t)
#pragma unroll
      for (int jj = 0; jj < 4; ++jj)
        a2[t][jj] = __builtin_amdgcn_cvt_pkrtz(fA[2 * jj][t], fA[2 * jj + 1][t]);

    // ---- 21 dx × 4 w × 4 c-pairs of dot2 ----
    const half2_t* lb = (const half2_t*)&lds[hf][0];
#pragma unroll
    for (int dx = 0; dx < PATCH_; ++dx) {
#pragma unroll
      for (int t = 0; t < 4; ++t) {
        const int p = wl + 32 * t + 2 * dx;   // position in staged row
#pragma unroll
        for (int jj = 0; jj < 4; ++jj)
          acc[t][dx] = fdot2f(a2[t][jj], lb[p * 4 + jj], acc[t][dx]);
      }
    }
  }

  // ---- epilogue: normalize, leaky-relu, store ----
  if (dyi < PATCH_) {
    const float s = 1.f / (float)C_;
#pragma unroll
    for (int dx = 0; dx < PATCH_; ++dx) {
      const size_t obase =
          (((size_t)b * (PATCH_ * PATCH_) + (size_t)(dyi * PATCH_ + dx)) * H_ + (size_t)h) * W_;
#pragma unroll
      for (int t = 0; t < 4; ++t) {
        float v = acc[t][dx] * s;
        v = (v >= 0.f) ? v : 0.1f * v;
        out[obase + (size_t)(wl + 32 * t)] = v;
      }
    }
  }
}

extern "C" void kernel_launch(void* const* d_in, const int* in_sizes, int n_in,
                              void* d_out, int out_size, void* d_ws, size_t ws_size,
                              hipStream_t stream) {
  (void)in_sizes; (void)n_in; (void)d_ws; (void)ws_size; (void)out_size;
  const float* in1 = (const float*)d_in[0];
  const float* in2 = (const float*)d_in[1];
  float* out = (float*)d_out;

  dim3 grid(B_ * H_ * NDY_);   // 8*96*11 = 8448, dy fastest for in1-row L2 reuse
  dim3 block(64);
  corr_kernel<<<grid, block, 0, stream>>>(in1, in2, out);
}

// Round 4
// 516.024 us; speedup vs baseline: 1.0329x; 1.0329x over previous
//
#include <hip/hip_runtime.h>

#define B_ 8
#define C_ 256
#define H_ 96
#define W_ 128
#define HW_ (H_*W_)
#define PATCH_ 21
#define MAXD_ 20
#define P2_ 168                 // staged positions per dy row
#define NBLK_ (B_*H_*11)        // 8448

typedef __fp16 half2_t __attribute__((ext_vector_type(2)));
typedef __fp16 h8_t    __attribute__((ext_vector_type(8)));
typedef float  f4_t    __attribute__((ext_vector_type(4)));

__device__ __forceinline__ float fdot2f(half2_t a, half2_t b, float c) {
  return __builtin_amdgcn_fdot2(a, b, c, false);
}
__device__ __forceinline__ int swz(int pos) { return pos ^ ((pos >> 3) & 7); }

__global__ __launch_bounds__(64, 2) void corr_kernel(
    const float* __restrict__ in1,
    const float* __restrict__ in2,
    float* __restrict__ out) {
  __shared__ h8_t lds[2 * P2_];   // [dyidx][swizzled pos], 8 ch as halves

  const int tid = threadIdx.x;
  const int l   = tid & 15;          // w-lane: w0 = 8*l covers W=128
  const int q   = (tid >> 4) & 1;    // dx half: 0 -> dx 0..10, 1 -> dx 11..20
  const int gdy = tid >> 5;          // dy sub-index within block

  // XCD-chunked swizzle: each XCD gets a contiguous 1056-block range (= one b)
  int bid = blockIdx.x;
  bid = (bid & 7) * (NBLK_ / 8) + (bid >> 3);
  const int dyb = bid % 11;
  const int h   = (bid / 11) % H_;
  const int b   = bid / (11 * H_);

  const int dy   = 2 * dyb + gdy;    // 0..21 (21 = pad, store-masked)
  const int w0   = 8 * l;
  const int rel0 = 20 * q;           // q=1 computes dx=10..20, stores 11..20

  float acc[8][11];
#pragma unroll
  for (int j = 0; j < 8; ++j)
#pragma unroll
    for (int i = 0; i < 11; ++i) acc[j][i] = 0.f;

  const int ldsbase = gdy * P2_;

  for (int c0 = 0; c0 < C_; c0 += 8) {
    __syncthreads();
    // ---- stage 2 dy rows x 168 pos x 8 ch (f32 -> packed f16) ----
#pragma unroll
    for (int s = tid; s < 2 * P2_; s += 64) {
      const int dyidx = (s >= P2_) ? 1 : 0;
      const int pos = s - P2_ * dyidx;
      const int h2 = h + 2 * (2 * dyb + dyidx) - MAXD_;
      const int w2 = pos - MAXD_;
      const bool v = ((unsigned)h2 < (unsigned)H_) && ((unsigned)w2 < (unsigned)W_);
      float f[8];
      if (v) {
        const float* bp = in2 + ((size_t)(b * C_ + c0) * H_ + h2) * W_ + w2;
#pragma unroll
        for (int j = 0; j < 8; ++j) f[j] = bp[(size_t)j * HW_];
      } else {
#pragma unroll
        for (int j = 0; j < 8; ++j) f[j] = 0.f;
      }
      h8_t pk;
#pragma unroll
      for (int jj = 0; jj < 4; ++jj) {
        half2_t p2 = __builtin_amdgcn_cvt_pkrtz(f[2 * jj], f[2 * jj + 1]);
        pk[2 * jj]     = p2.x;
        pk[2 * jj + 1] = p2.y;
      }
      lds[dyidx * P2_ + swz(pos)] = pk;
    }

    // ---- A fragments: 8 consecutive w, 8 ch, packed to half2 pairs ----
    const float* a_base = in1 + ((size_t)(b * C_ + c0) * H_ + h) * W_ + w0;
    half2_t a2[8][4];
#pragma unroll
    for (int jj = 0; jj < 4; ++jj) {
      f4_t lo0 = *(const f4_t*)(a_base + (size_t)(2 * jj) * HW_);
      f4_t lo1 = *(const f4_t*)(a_base + (size_t)(2 * jj) * HW_ + 4);
      f4_t hi0 = *(const f4_t*)(a_base + (size_t)(2 * jj + 1) * HW_);
      f4_t hi1 = *(const f4_t*)(a_base + (size_t)(2 * jj + 1) * HW_ + 4);
#pragma unroll
      for (int j = 0; j < 4; ++j) {
        half2_t p = __builtin_amdgcn_cvt_pkrtz(lo0[j], hi0[j]);
        a2[j][jj] = p;
        half2_t p1 = __builtin_amdgcn_cvt_pkrtz(lo1[j], hi1[j]);
        a2[j + 4][jj] = p1;
      }
    }
    __syncthreads();

    // ---- preload 8-position register window (slot = rel & 7) ----
    h8_t wv[8];
#pragma unroll
    for (int k = 0; k < 8; ++k)
      wv[k] = lds[ldsbase + swz(w0 + rel0 + k)];

    // ---- 11 dx steps: 32 dot2 each, slide window by 2 ----
#pragma unroll
    for (int i = 0; i < 11; ++i) {
#pragma unroll
      for (int j = 0; j < 8; ++j) {
        const h8_t wj = wv[(2 * i + j) & 7];
#pragma unroll
        for (int jj = 0; jj < 4; ++jj) {
          half2_t bb;
          bb.x = wj[2 * jj];
          bb.y = wj[2 * jj + 1];
          acc[j][i] = fdot2f(a2[j][jj], bb, acc[j][i]);
        }
      }
      if (i < 10) {
        wv[(2 * i + 8) & 7] = lds[ldsbase + swz(w0 + rel0 + 2 * i + 8)];
        wv[(2 * i + 9) & 7] = lds[ldsbase + swz(w0 + rel0 + 2 * i + 9)];
      }
    }
  }

  // ---- epilogue ----
  if (dy < PATCH_) {
    const float s = 1.f / (float)C_;
#pragma unroll
    for (int i = 0; i < 11; ++i) {
      if (q && i == 0) continue;          // q=1's i=0 (dx=10) is duplicate work
      const int dx = 10 * q + i;
      float* ob = out + ((size_t)(b * (PATCH_ * PATCH_) + dy * PATCH_ + dx) * H_ + h) * W_ + w0;
      f4_t v0, v1;
#pragma unroll
      for (int j = 0; j < 4; ++j) {
        float x = acc[j][i] * s;
        v0[j] = (x >= 0.f) ? x : 0.1f * x;
        float y = acc[j + 4][i] * s;
        v1[j] = (y >= 0.f) ? y : 0.1f * y;
      }
      *(f4_t*)ob = v0;
      *(f4_t*)(ob + 4) = v1;
    }
  }
}

extern "C" void kernel_launch(void* const* d_in, const int* in_sizes, int n_in,
                              void* d_out, int out_size, void* d_ws, size_t ws_size,
                              hipStream_t stream) {
  (void)in_sizes; (void)n_in; (void)d_ws; (void)ws_size; (void)out_size;
  const float* in1 = (const float*)d_in[0];
  const float* in2 = (const float*)d_in[1];
  float* out = (float*)d_out;
  corr_kernel<<<dim3(NBLK_), dim3(64), 0, stream>>>(in1, in2, out);
}